// Round 4
// baseline (454.708 us; speedup 1.0000x reference)
//
#include <hip/hip_runtime.h>

// OccurrencePool R8: occ + feat merged into ONE kernel (k_of), one block per
// 128-voxel s-tile, 8 waves, 160KB LDS. The full x tile (128KB) is staged
// into LDS ONCE (16 glds/wave, two counted vmcnt waits), then ALL GEMMs
// (occ chain + r1 for all 4 cb slices + contraction) run from LDS with
// weight fragments loaded directly from L2-hot global (<1MB total weights)
// inside barrier-free K-loops. This kills the R4/R7 structure where k_occ +
// k_feat spent ~170us on 49 GF: 512 tiny blocks, depth-1 prefetch, 2
// waves/SIMD, x read 5x. Here x is read from HBM exactly once and the
// occP global round-trip is gone.
//   r1  = relu(W1 x + b1)                          (bf16 MFMA, 34.4 GF)
//   occ = |W3 relu(W2o relu(W1o x + b1o) + b2o)|   (bf16 MFMA, 10.2 GF)
//   M[b,o,j]   = sum_s occ[b,o,s] r1[b,j,s]        (bf16 MFMA, 4.3 GF)
//   out[b,o,c] = (sum_j M[o,j] W2[c,j] + b2[c]*sumocc[b,o]) / S
// Tile layout (per 128-voxel tile, per 64-wide K chunk kc):
//   linear = kc*8192 + k8*1024 + row*8 + k0   (shorts; k8=(k>>3)&7, k0=k&7)

#define S_TOT 16384  // T*H*W per batch

typedef __attribute__((ext_vector_type(8))) short bf8_t;  // 8 bf16 (4 VGPRs)
typedef __attribute__((ext_vector_type(4))) short s4_t;   // 4 bf16
typedef __attribute__((ext_vector_type(4))) float f4_t;

#define MFMA __builtin_amdgcn_mfma_f32_16x16x32_bf16

#define BAR_FENCE() do { __builtin_amdgcn_s_barrier(); \
                         asm volatile("" ::: "memory"); } while (0)
#define WAIT_VM8()  asm volatile("s_waitcnt vmcnt(8)" ::: "memory")
#define WAIT_VM0()  asm volatile("s_waitcnt vmcnt(0)" ::: "memory")
#define WAIT_LGKM0() asm volatile("s_waitcnt lgkmcnt(0)" ::: "memory")

__device__ __forceinline__ short f2bf(float f) {
  union { float f; unsigned u; } v; v.f = f;
  unsigned u = v.u + 0x7FFFu + ((v.u >> 16) & 1u);  // RNE
  return (short)(u >> 16);
}

__device__ __forceinline__ void glds16(const void* g, void* l) {
  __builtin_amdgcn_global_load_lds(
      (const __attribute__((address_space(1))) void*)g,
      (__attribute__((address_space(3))) void*)l, 16, 0, 0);
}

// ------ x transpose + weight convert (merged) -------------------------------
__global__ __launch_bounds__(256) void k_transpose(
    const float* __restrict__ x, short* __restrict__ xTs,
    const float* __restrict__ w1, const float* __restrict__ wo1,
    const float* __restrict__ wo2, const float* __restrict__ wo3,
    short* __restrict__ wb) {
  __shared__ float tls[64][65];
  const int sb = blockIdx.x, cb = blockIdx.y, b = blockIdx.z;
  const int t = threadIdx.x;
  if (cb == 0 && b == 0) {  // 256 blocks x 256 thr: weight convert
    for (int i = sb * 256 + t; i < 339968; i += 65536) {
      if (i < 262144) {  // w1[j][k] -> [jc][kc][k8][j&127][k0]
        const int j = i >> 9, k = i & 511;
        const int di = ((j >> 7) * 8 + (k >> 6)) * 8192 +
                       ((k >> 3) & 7) * 1024 + (j & 127) * 8 + (k & 7);
        wb[di] = f2bf(w1[i]);
      } else if (i < 327680) {  // wo1[c4][k] -> [kc][k8][c4][k0]
        const int e = i - 262144;
        const int c4 = e >> 9, k = e & 511;
        const int di = 262144 + (k >> 6) * 8192 + ((k >> 3) & 7) * 1024 +
                       c4 * 8 + (k & 7);
        wb[di] = f2bf(wo1[e]);
      } else if (i < 335872) {
        wb[i] = f2bf(wo2[i - 327680]);
      } else {
        wb[i] = f2bf(wo3[i - 335872]);
      }
    }
  }
  {
    const int cr = t >> 2, ss = (t & 3) * 16;
    const float* src = x + ((size_t)b * 512 + cb * 64 + cr) * S_TOT + sb * 64 + ss;
    f4_t v0 = *(const f4_t*)(src);
    f4_t v1 = *(const f4_t*)(src + 4);
    f4_t v2 = *(const f4_t*)(src + 8);
    f4_t v3 = *(const f4_t*)(src + 12);
#pragma unroll
    for (int j = 0; j < 4; ++j) {
      tls[cr][ss + j]      = v0[j];
      tls[cr][ss + 4 + j]  = v1[j];
      tls[cr][ss + 8 + j]  = v2[j];
      tls[cr][ss + 12 + j] = v3[j];
    }
  }
  __syncthreads();
  {
    const int sr = t >> 2, cs = (t & 3) * 16;  // k window cs..cs+15 (2 chunks)
    alignas(16) short tmp[16];
#pragma unroll
    for (int j = 0; j < 16; ++j) tmp[j] = f2bf(tls[cs + j][sr]);
    const int st = sb >> 1, s_in = (sb & 1) * 64 + sr, k8 = cs >> 3;
    short* base = xTs + (((size_t)(b * 128 + st) * 8 + cb) * 8 + k8) * 1024 +
                  s_in * 8;
    *(bf8_t*)base          = *(const bf8_t*)&tmp[0];
    *(bf8_t*)(base + 1024) = *(const bf8_t*)&tmp[8];
  }
}

// ---------------- fused occ + feat megakernel -------------------------------
// block = one s-tile (128 voxels); 8 waves; LDS = xs(128K) | aux(32K).
// aux timeline: h1s(32K) -> h2s(aux[0:16K)) -> occS(aux[16K:32K)) -> af regs
//               -> r1s(32K) per cb slice.
__global__ __launch_bounds__(512, 2) void k_of(
    const short* __restrict__ xTs, const short* __restrict__ w1s,
    const float* __restrict__ b1,
    const short* __restrict__ wo1, const short* __restrict__ wo2,
    const short* __restrict__ wo3, const float* __restrict__ bo1,
    const float* __restrict__ bo2,
    float* __restrict__ M, float* __restrict__ sumocc) {
  __shared__ short smem[81920];        // 160 KiB exactly
  short* const xs   = smem;            // 128KB: 8 chunks x 8192 shorts
  short* const aux  = smem + 65536;    // 32KB
  short* const h1s  = aux;             // 32KB [c4chunk16][s128][k0 8]
  short* const h2s  = aux;             // 16KB [c8chunk8][s128][k0]
  short* const occS = aux + 8192;      // 16KB [s8 16][o 64][s0 8]
  short* const r1s  = aux;             // 32KB [schunk16][j128][k0]
  const int tile = blockIdx.x, b = blockIdx.y;
  const int t = threadIdx.x, lane = t & 63, wv = t >> 6;  // wv 0..7
  const int q = lane >> 4, li = lane & 15;
  const int mh1 = (wv & 1) * 64;   // 64-wide m strip (c4 rows / s rows)
  const int nhs = (wv >> 1) * 32;  // 32-wide n strip (s or j cols)
  const int mh2 = (wv & 1) * 32;   // 32-wide m strip (c8 / o rows)
  const short* xTb = xTs + (size_t)(b * 128 + tile) * 65536;
  const f4_t fz = {0.f, 0.f, 0.f, 0.f};

  // ---- stage all 8 x-chunks (128KB) : 16 glds/wave, counted waits ----------
#pragma unroll
  for (int c = 0; c < 8; ++c) {
#pragma unroll
    for (int j = 0; j < 2; ++j) {
      const int off = c * 8192 + (wv * 2 + j) * 512;
      glds16(xTb + off + lane * 8, xs + off);
    }
  }
  WAIT_VM8();   // chunks 0-3 landed (no other VMEM issued yet)
  BAR_FENCE();

  // ---- phase 1: h1 = relu(Wo1 @ x + b1o)  [c4=128 x s=128], K=512 ----------
  f4_t hcc[4][2];
#pragma unroll
  for (int i = 0; i < 4; ++i) { hcc[i][0] = fz; hcc[i][1] = fz; }

#define OCC_CHUNK(c)                                                        \
  {                                                                         \
    const short* og = wo1 + (c) * 8192;                                     \
    const short* xc = xs + (c) * 8192;                                      \
    _Pragma("unroll")                                                       \
    for (int kk = 0; kk < 2; ++kk) {                                        \
      const int pl = (4 * kk + q) * 128;                                    \
      bf8_t a[4], bb[2];                                                    \
      _Pragma("unroll")                                                     \
      for (int ma = 0; ma < 4; ++ma)                                        \
        a[ma] = *(const bf8_t*)&og[(pl + mh1 + 16 * ma + li) * 8];          \
      _Pragma("unroll")                                                     \
      for (int nb = 0; nb < 2; ++nb)                                        \
        bb[nb] = *(const bf8_t*)&xc[(pl + nhs + 16 * nb + li) * 8];         \
      _Pragma("unroll")                                                     \
      for (int ma = 0; ma < 4; ++ma)                                        \
        _Pragma("unroll")                                                   \
        for (int nb = 0; nb < 2; ++nb)                                      \
          hcc[ma][nb] = MFMA(a[ma], bb[nb], hcc[ma][nb], 0, 0, 0);          \
    }                                                                       \
  }

  OCC_CHUNK(0) OCC_CHUNK(1) OCC_CHUNK(2) OCC_CHUNK(3)
  WAIT_VM0();   // chunks 4-7 landed
  BAR_FENCE();
  OCC_CHUNK(4) OCC_CHUNK(5) OCC_CHUNK(6) OCC_CHUNK(7)
#undef OCC_CHUNK

  // h1s write (aux, disjoint from xs -> no pre-barrier needed)
#pragma unroll
  for (int ma = 0; ma < 4; ++ma) {
    const int c40 = mh1 + 16 * ma + 4 * q;
    f4_t bv = *(const f4_t*)(bo1 + c40);
#pragma unroll
    for (int nb = 0; nb < 2; ++nb) {
      const int sl = nhs + 16 * nb + li;
      s4_t p;
#pragma unroll
      for (int r = 0; r < 4; ++r) p[r] = f2bf(fmaxf(hcc[ma][nb][r] + bv[r], 0.0f));
      *(s4_t*)&h1s[((c40 >> 3) * 128 + sl) * 8 + (c40 & 7)] = p;
    }
  }
  WAIT_LGKM0();
  BAR_FENCE();  // h1s visible

  // ---- phase 2: h2 = relu(Wo2 @ h1 + b2o)  [c8=64 x s=128], K=128 ----------
  f4_t a2[2][2];
#pragma unroll
  for (int i = 0; i < 2; ++i) { a2[i][0] = fz; a2[i][1] = fz; }
#pragma unroll
  for (int kk = 0; kk < 4; ++kk) {
    const int pl = (4 * kk + q) * 128;
    bf8_t a[2], bb[2];
#pragma unroll
    for (int ma = 0; ma < 2; ++ma)
      a[ma] = *(const bf8_t*)(wo2 + (size_t)(mh2 + 16 * ma + li) * 128 +
                              kk * 32 + q * 8);
#pragma unroll
    for (int nb = 0; nb < 2; ++nb)
      bb[nb] = *(const bf8_t*)&h1s[(pl + nhs + 16 * nb + li) * 8];
#pragma unroll
    for (int ma = 0; ma < 2; ++ma)
#pragma unroll
      for (int nb = 0; nb < 2; ++nb)
        a2[ma][nb] = MFMA(a[ma], bb[nb], a2[ma][nb], 0, 0, 0);
  }
  BAR_FENCE();  // all h1s reads retired (reads complete before their MFMAs)
  // h2s write into aux[0:16K)
#pragma unroll
  for (int ma = 0; ma < 2; ++ma) {
    const int c80 = mh2 + 16 * ma + 4 * q;
    f4_t bv = *(const f4_t*)(bo2 + c80);
#pragma unroll
    for (int nb = 0; nb < 2; ++nb) {
      const int sl = nhs + 16 * nb + li;
      s4_t p;
#pragma unroll
      for (int r = 0; r < 4; ++r) p[r] = f2bf(fmaxf(a2[ma][nb][r] + bv[r], 0.0f));
      *(s4_t*)&h2s[((c80 >> 3) * 128 + sl) * 8 + (c80 & 7)] = p;
    }
  }
  WAIT_LGKM0();
  BAR_FENCE();  // h2s visible

  // ---- phase 3: occ = |Wo3 @ h2|  [o=64 x s=128], K=64 ---------------------
  f4_t a3[2][2];
#pragma unroll
  for (int i = 0; i < 2; ++i) { a3[i][0] = fz; a3[i][1] = fz; }
#pragma unroll
  for (int kk = 0; kk < 2; ++kk) {
    const int pl = (4 * kk + q) * 128;
    bf8_t a[2], bb[2];
#pragma unroll
    for (int ma = 0; ma < 2; ++ma)
      a[ma] = *(const bf8_t*)(wo3 + (size_t)(mh2 + 16 * ma + li) * 64 +
                              kk * 32 + q * 8);
#pragma unroll
    for (int nb = 0; nb < 2; ++nb)
      bb[nb] = *(const bf8_t*)&h2s[(pl + nhs + 16 * nb + li) * 8];
#pragma unroll
    for (int ma = 0; ma < 2; ++ma)
#pragma unroll
      for (int nb = 0; nb < 2; ++nb)
        a3[ma][nb] = MFMA(a[ma], bb[nb], a3[ma][nb], 0, 0, 0);
  }
  // occS write at aux[16K:32K) — disjoint from h2s, no barrier needed first
#pragma unroll
  for (int ma = 0; ma < 2; ++ma)
#pragma unroll
    for (int nb = 0; nb < 2; ++nb) {
      const int o = mh2 + 16 * ma + 4 * q;
      const int sl = nhs + 16 * nb + li;
#pragma unroll
      for (int r = 0; r < 4; ++r)
        occS[(sl >> 3) * 512 + (o + r) * 8 + (sl & 7)] = f2bf(fabsf(a3[ma][nb][r]));
    }
  // sumocc[b][o] += sum_s |occ|
#pragma unroll
  for (int ma = 0; ma < 2; ++ma)
#pragma unroll
    for (int r = 0; r < 4; ++r) {
      float v = fabsf(a3[ma][0][r]) + fabsf(a3[ma][1][r]);
#pragma unroll
      for (int m = 1; m < 16; m <<= 1) v += __shfl_xor(v, m, 64);
      if (li == 0) atomicAdd(&sumocc[b * 64 + mh2 + 16 * ma + 4 * q + r], v);
    }
  WAIT_LGKM0();
  BAR_FENCE();  // occS visible

  // af preload: contraction A-frags (occ), then aux is free
  bf8_t af[4][2];
#pragma unroll
  for (int kc = 0; kc < 4; ++kc)
#pragma unroll
    for (int ma = 0; ma < 2; ++ma)
      af[kc][ma] = *(const bf8_t*)&occS[((kc * 4 + q) * 64 + mh2 + 16 * ma + li) * 8];
  WAIT_LGKM0();
  BAR_FENCE();  // af in regs everywhere; aux reusable as r1s

  // ---- phase 4: per cb slice: r1 GEMM (K=512) + contraction into macc ------
  f4_t macc[4][2][2];
#pragma unroll
  for (int cb = 0; cb < 4; ++cb)
#pragma unroll
    for (int i = 0; i < 2; ++i) { macc[cb][i][0] = fz; macc[cb][i][1] = fz; }

#pragma unroll
  for (int cb = 0; cb < 4; ++cb) {
    const short* w1b = w1s + cb * 65536;
    const float bias0 = b1[cb * 128 + nhs + li];
    const float bias1 = b1[cb * 128 + nhs + 16 + li];
    f4_t racc[4][2];
#pragma unroll
    for (int i = 0; i < 4; ++i) { racc[i][0] = fz; racc[i][1] = fz; }
#pragma unroll 2
    for (int c = 0; c < 8; ++c) {
      const short* xc = xs + c * 8192;
      const short* wc = w1b + c * 8192;
#pragma unroll
      for (int kk = 0; kk < 2; ++kk) {
        const int pl = (4 * kk + q) * 128;
        bf8_t a[4], bb[2];
#pragma unroll
        for (int ma = 0; ma < 4; ++ma)
          a[ma] = *(const bf8_t*)&xc[(pl + mh1 + 16 * ma + li) * 8];
#pragma unroll
        for (int nb = 0; nb < 2; ++nb)
          bb[nb] = *(const bf8_t*)&wc[(pl + nhs + 16 * nb + li) * 8];
#pragma unroll
        for (int ma = 0; ma < 4; ++ma)
#pragma unroll
          for (int nb = 0; nb < 2; ++nb)
            racc[ma][nb] = MFMA(a[ma], bb[nb], racc[ma][nb], 0, 0, 0);
      }
    }
    BAR_FENCE();  // previous cb's r1s contraction reads retired
    // r1 = relu(racc + b1) -> r1s planar [schunk][j]
#pragma unroll
    for (int ma = 0; ma < 4; ++ma) {
      const int sl0 = mh1 + 16 * ma + 4 * q;
#pragma unroll
      for (int nb = 0; nb < 2; ++nb) {
        const int jl = nhs + 16 * nb + li;
        const float bs = nb ? bias1 : bias0;
        s4_t p;
#pragma unroll
        for (int r = 0; r < 4; ++r)
          p[r] = f2bf(fmaxf(racc[ma][nb][r] + bs, 0.0f));
        *(s4_t*)&r1s[((sl0 >> 3) * 128 + jl) * 8 + (sl0 & 7)] = p;
      }
    }
    WAIT_LGKM0();
    BAR_FENCE();  // r1s visible
    // contraction: macc[o][j] += occ[o][s] * r1[j][s]  (K = s = 128)
#pragma unroll
    for (int kc = 0; kc < 4; ++kc) {
      const int pl = (4 * kc + q) * 128;
      bf8_t bb[2];
#pragma unroll
      for (int nb = 0; nb < 2; ++nb)
        bb[nb] = *(const bf8_t*)&r1s[(pl + nhs + 16 * nb + li) * 8];
#pragma unroll
      for (int ma = 0; ma < 2; ++ma)
#pragma unroll
        for (int nb = 0; nb < 2; ++nb)
          macc[cb][ma][nb] = MFMA(af[kc][ma], bb[nb], macc[cb][ma][nb], 0, 0, 0);
    }
  }
  // flush partial M
#pragma unroll
  for (int cb = 0; cb < 4; ++cb)
#pragma unroll
    for (int ma = 0; ma < 2; ++ma)
#pragma unroll
      for (int nb = 0; nb < 2; ++nb) {
        const int jg = cb * 128 + nhs + 16 * nb + li;
#pragma unroll
        for (int r = 0; r < 4; ++r) {
          const int o = mh2 + 16 * ma + 4 * q + r;
          atomicAdd(&M[((size_t)b * 64 + o) * 512 + jg], macc[cb][ma][nb][r]);
        }
      }
}

// ---------------- epilogue: out = (M @ W2^T + sumocc * b2^T) / S ------------
__global__ __launch_bounds__(256) void k_out(
    const float* __restrict__ M, const float* __restrict__ sumocc,
    const float* __restrict__ w2, const float* __restrict__ b2,
    float* __restrict__ out) {
  const int cg = blockIdx.x, og = blockIdx.y, b = blockIdx.z;
  const int t = threadIdx.x;
  const int o = og * 16 + (t >> 4);
  const int c = cg * 16 + (t & 15);
  const float* mr = M + ((size_t)b * 64 + o) * 512;
  const float* wr = w2 + (size_t)c * 512;
  float s0 = 0.f, s1 = 0.f, s2 = 0.f, s3 = 0.f;
#pragma unroll 4
  for (int j = 0; j < 512; j += 16) {
    f4_t m0 = *(const f4_t*)(mr + j);
    f4_t m1 = *(const f4_t*)(mr + j + 4);
    f4_t m2 = *(const f4_t*)(mr + j + 8);
    f4_t m3 = *(const f4_t*)(mr + j + 12);
    f4_t w0 = *(const f4_t*)(wr + j);
    f4_t w1 = *(const f4_t*)(wr + j + 4);
    f4_t w2v = *(const f4_t*)(wr + j + 8);
    f4_t w3 = *(const f4_t*)(wr + j + 12);
    s0 += m0[0]*w0[0] + m0[1]*w0[1] + m0[2]*w0[2] + m0[3]*w0[3];
    s1 += m1[0]*w1[0] + m1[1]*w1[1] + m1[2]*w1[2] + m1[3]*w1[3];
    s2 += m2[0]*w2v[0] + m2[1]*w2v[1] + m2[2]*w2v[2] + m2[3]*w2v[3];
    s3 += m3[0]*w3[0] + m3[1]*w3[1] + m3[2]*w3[2] + m3[3]*w3[3];
  }
  out[((size_t)b * 64 + o) * 512 + c] =
      (((s0 + s1) + (s2 + s3)) + sumocc[b * 64 + o] * b2[c]) * (1.0f / 16384.0f);
}

// ---------------- launch ----------------------------------------------------
// ws layout (bytes):
//   0         xTs     4*16384*512 bf16 = 67108864   (swizzled tiles)
//   67108864  wb      339968 bf16 (w1s | wo1s | wo2 | wo3) = 679936
//   76177408  M       4*64*512 fp32    = 524288
//   76701696  sumocc  256 fp32         = 1024
extern "C" void kernel_launch(void* const* d_in, const int* in_sizes, int n_in,
                              void* d_out, int out_size, void* d_ws, size_t ws_size,
                              hipStream_t stream) {
  (void)in_sizes; (void)n_in; (void)out_size; (void)ws_size;
  const float* x      = (const float*)d_in[0];
  const float* w_add1 = (const float*)d_in[1];
  const float* b_add1 = (const float*)d_in[2];
  const float* w_add2 = (const float*)d_in[3];
  const float* b_add2 = (const float*)d_in[4];
  const float* w_occ1 = (const float*)d_in[5];
  const float* b_occ1 = (const float*)d_in[6];
  const float* w_occ2 = (const float*)d_in[7];
  const float* b_occ2 = (const float*)d_in[8];
  const float* w_occ3 = (const float*)d_in[9];

  char* ws = (char*)d_ws;
  short* xTs     = (short*)(ws);
  short* wb      = (short*)(ws + 67108864);
  float* M       = (float*)(ws + 76177408);
  float* sumocc  = (float*)(ws + 76701696);

  hipMemsetAsync(M, 0, 524288 + 1024, stream);  // M + sumocc
  k_transpose<<<dim3(256, 8, 4), dim3(256), 0, stream>>>(
      x, xTs, w_add1, w_occ1, w_occ2, w_occ3, wb);

  const short* w1sp = wb;
  const short* wbo1 = wb + 262144;
  const short* wbo2 = wb + 327680;
  const short* wbo3 = wb + 335872;
  k_of<<<dim3(128, 4), dim3(512), 0, stream>>>(
      xTs, w1sp, b_add1, wbo1, wbo2, wbo3, b_occ1, b_occ2, M, sumocc);
  k_out<<<dim3(32, 4, 4), dim3(256), 0, stream>>>(M, sumocc, w_add2, b_add2,
                                                  (float*)d_out);
}

// Round 5
// 375.894 us; speedup vs baseline: 1.2097x; 1.2097x over previous
//
#include <hip/hip_runtime.h>

// OccurrencePool R9 = R7 (best, 397us) with the HIDDEN half optimized:
//  - k_out: was per-thread 4KB global streams (512MB chip-wide L2 broadcast
//    traffic, latency-bound). Now LDS-stages the 32KB M-tile + 32KB w2-tile
//    per block with coalesced f4 copies (32MB total) and computes from LDS.
//  - k_transpose: 8192 -> 4096 blocks; each block does one full 128-voxel
//    tile (2x work/thread, amortizes the LDS round trip).
//  - k_occ / k_feat: unchanged from R7 (counted-vmcnt pipeline, 88us).
// R5/R6/R8 lessons: fusion replicates x 4x; direct-global frags overfetch
// 10x; 160KB-LDS megakernel = 1 block/CU kills overlap. Staged R7 is best.
//   r1  = relu(W1 x + b1)                          (bf16 MFMA, 34.4 GF)
//   occ = |W3 relu(W2o relu(W1o x + b1o) + b2o)|   (bf16 MFMA, 10.2 GF)
//   M[b,o,j]   = sum_s occ[b,o,s] r1[b,j,s]        (bf16 MFMA, 4.3 GF)
//   out[b,o,c] = (sum_j M[o,j] W2[c,j] + b2[c]*sumocc[b,o]) / S
// Tile layout (per 128-voxel tile, per 64-wide K chunk kc):
//   linear = kc*8192 + k8*1024 + row*8 + k0   (shorts; k8=(k>>3)&7, k0=k&7)

#define S_TOT 16384  // T*H*W per batch

typedef __attribute__((ext_vector_type(8))) short bf8_t;  // 8 bf16 (4 VGPRs)
typedef __attribute__((ext_vector_type(4))) short s4_t;   // 4 bf16
typedef __attribute__((ext_vector_type(4))) float f4_t;

#define MFMA __builtin_amdgcn_mfma_f32_16x16x32_bf16

// raw barrier + code-motion fence (prevent LDS reads hoisting above barrier)
#define BAR_FENCE() do { __builtin_amdgcn_s_barrier(); \
                         asm volatile("" ::: "memory"); } while (0)
#define WAIT_VM8()  asm volatile("s_waitcnt vmcnt(8)" ::: "memory")
#define WAIT_VM0()  asm volatile("s_waitcnt vmcnt(0)" ::: "memory")
#define WAIT_LGKM0() asm volatile("s_waitcnt lgkmcnt(0)" ::: "memory")

__device__ __forceinline__ short f2bf(float f) {
  union { float f; unsigned u; } v; v.f = f;
  unsigned u = v.u + 0x7FFFu + ((v.u >> 16) & 1u);  // RNE
  return (short)(u >> 16);
}

__device__ __forceinline__ void glds16(const void* g, void* l) {
  __builtin_amdgcn_global_load_lds(
      (const __attribute__((address_space(1))) void*)g,
      (__attribute__((address_space(3))) void*)l, 16, 0, 0);
}

// Contiguous 16KB global -> LDS copy (layouts identical). 4 glds/wave, each
// lane-contiguous 1KB: g + off + lane*8 shorts; HW adds lane*16B on LDS side.
__device__ __forceinline__ void stage16k(const short* g, short* lds,
                                         int wv, int lane) {
#pragma unroll
  for (int i = 0; i < 4; ++i) {
    const int off = (wv * 4 + i) * 512;
    glds16(g + off + lane * 8, lds + off);
  }
}

// ------ x transpose + weight convert (merged) -------------------------------
// One block per full 128-voxel tile: x[b][c][s] fp32 ->
// xTs[b][st][kc][k8][s(128)][k0] bf16. Blocks (y==0,z==0) also grid-stride
// the weight fp32->bf16 convert+swizzle.
__global__ __launch_bounds__(256) void k_transpose(
    const float* __restrict__ x, short* __restrict__ xTs,
    const float* __restrict__ w1, const float* __restrict__ wo1,
    const float* __restrict__ wo2, const float* __restrict__ wo3,
    short* __restrict__ wb) {
  __shared__ float tls[64][129];  // [c(64)][s(128)+pad]
  const int sb = blockIdx.x, cb = blockIdx.y, b = blockIdx.z;  // sb = st
  const int t = threadIdx.x;
  if (cb == 0 && b == 0) {  // 128 blocks x 256 thr: weight convert
    for (int i = sb * 256 + t; i < 339968; i += 32768) {
      if (i < 262144) {  // w1[j][k] -> [jc][kc][k8][j&127][k0]
        const int j = i >> 9, k = i & 511;
        const int di = ((j >> 7) * 8 + (k >> 6)) * 8192 +
                       ((k >> 3) & 7) * 1024 + (j & 127) * 8 + (k & 7);
        wb[di] = f2bf(w1[i]);
      } else if (i < 327680) {  // wo1[c4][k] -> [kc][k8][c4][k0]
        const int e = i - 262144;
        const int c4 = e >> 9, k = e & 511;
        const int di = 262144 + (k >> 6) * 8192 + ((k >> 3) & 7) * 1024 +
                       c4 * 8 + (k & 7);
        wb[di] = f2bf(wo1[e]);
      } else if (i < 335872) {
        wb[i] = f2bf(wo2[i - 327680]);
      } else {
        wb[i] = f2bf(wo3[i - 335872]);
      }
    }
  }
  {
    const int cr = t >> 2, ss = (t & 3) * 32;  // 64B-contiguous per thread x2
    const float* src = x + ((size_t)b * 512 + cb * 64 + cr) * S_TOT +
                       sb * 128 + ss;
#pragma unroll
    for (int k = 0; k < 8; ++k) {
      f4_t v = *(const f4_t*)(src + k * 4);
#pragma unroll
      for (int j = 0; j < 4; ++j) tls[cr][ss + k * 4 + j] = v[j];
    }
  }
  __syncthreads();
  {
#pragma unroll
    for (int h = 0; h < 2; ++h) {  // 512 items = 2 per thread
      const int id = h * 256 + t;
      const int s_in = id >> 2, cs = (id & 3) * 16, k8 = cs >> 3;
      alignas(16) short tmp[16];
#pragma unroll
      for (int j = 0; j < 16; ++j) tmp[j] = f2bf(tls[cs + j][s_in]);
      short* base = xTs + (((size_t)(b * 128 + sb) * 8 + cb) * 8 + k8) * 1024 +
                    s_in * 8;
      *(bf8_t*)base          = *(const bf8_t*)&tmp[0];
      *(bf8_t*)(base + 1024) = *(const bf8_t*)&tmp[8];
    }
  }
}

// ---------------- occ chain: 3 fused GEMMs per 128-voxel tile ---------------
// K-loop: counted-vmcnt pipeline, chunk i lives in buf[(i+1)&1].
// occP output layout per tile: [s8(16)][o(64)][s0(8)] = planar A-operand image
__global__ __launch_bounds__(256) void k_occ(
    const short* __restrict__ xTs, const short* __restrict__ wo1,
    const short* __restrict__ wo2, const short* __restrict__ wo3,
    const float* __restrict__ bo1, const float* __restrict__ bo2,
    short* __restrict__ occP, float* __restrict__ sumocc) {
  __shared__ short smem[32768];  // 64KB: buf0 | buf1 (32KB each)
  short* const buf0 = smem;
  short* const buf1 = smem + 16384;
  short* const h1s = buf0;   // 32KB planar [c4chunk][s] after K-loop
  short* const h2s = buf1;   // 16KB planar [c8chunk][s]
  const int tile = blockIdx.x, b = blockIdx.y;
  const int t = threadIdx.x, lane = t & 63, wv = t >> 6;
  const int q = lane >> 4, li = lane & 15;
  const int mh = (wv & 1) * 64, nh = (wv >> 1) * 64;
  const short* xTb = xTs + (size_t)(b * 128 + tile) * 65536;
  const f4_t fz = {0.f, 0.f, 0.f, 0.f};

  // phase 1: h1 = relu(Wo1 @ x + b1o)  [c4=128 x s=128], K=512, pipelined
  f4_t hcc[4][4];
#pragma unroll
  for (int i = 0; i < 4; ++i)
#pragma unroll
    for (int j = 0; j < 4; ++j) hcc[i][j] = fz;

  stage16k(xTb, buf1, wv, lane);          // chunk0 -> buf1
  stage16k(wo1, buf1 + 8192, wv, lane);
  for (int i = 0; i < 8; ++i) {
    BAR_FENCE();  // A: prev chunk's buffer reads retired by all waves
    if (i < 7) {
      short* nb_ = (i & 1) ? buf1 : buf0;  // chunk i+1 -> buf[i&1]^1 image
      stage16k(xTb + (i + 1) * 8192, nb_, wv, lane);
      stage16k(wo1 + (i + 1) * 8192, nb_ + 8192, wv, lane);
      WAIT_VM8();  // my chunk-i 8 glds landed; chunk-i+1's stay in flight
    } else {
      WAIT_VM0();
    }
    BAR_FENCE();  // B: everyone's chunk-i staged data visible
    const short* xs = (i & 1) ? buf0 : buf1;
    const short* wsp = xs + 8192;
#pragma unroll
    for (int kk = 0; kk < 2; ++kk) {
      const int pl = (4 * kk + q) * 128;
      bf8_t a[4], bb[4];
#pragma unroll
      for (int ma = 0; ma < 4; ++ma)
        a[ma] = *(const bf8_t*)&wsp[(pl + mh + 16 * ma + li) * 8];
#pragma unroll
      for (int nb = 0; nb < 4; ++nb)
        bb[nb] = *(const bf8_t*)&xs[(pl + nh + 16 * nb + li) * 8];
#pragma unroll
      for (int ma = 0; ma < 4; ++ma)
#pragma unroll
        for (int nb = 0; nb < 4; ++nb)
          hcc[ma][nb] = MFMA(a[ma], bb[nb], hcc[ma][nb], 0, 0, 0);
    }
  }
  WAIT_LGKM0();
  BAR_FENCE();  // chunk7 (buf0) reads retired everywhere; buf0 reusable
  // bias+relu -> h1s planar [c4chunk][s]
#pragma unroll
  for (int ma = 0; ma < 4; ++ma) {
    const int c40 = mh + 16 * ma + 4 * q;
    f4_t bv = *(const f4_t*)(bo1 + c40);
#pragma unroll
    for (int nb = 0; nb < 4; ++nb) {
      const int sl = nh + 16 * nb + li;
      s4_t p;
#pragma unroll
      for (int r = 0; r < 4; ++r) p[r] = f2bf(fmaxf(hcc[ma][nb][r] + bv[r], 0.0f));
      *(s4_t*)&h1s[((c40 >> 3) * 128 + sl) * 8 + (c40 & 7)] = p;
    }
  }
  __syncthreads();
  // phase 2: h2 = relu(Wo2 @ h1 + b2o)  [c8=64 x s=128], K=c4=128
  f4_t a2[4][2];
#pragma unroll
  for (int i = 0; i < 4; ++i) { a2[i][0] = fz; a2[i][1] = fz; }
#pragma unroll
  for (int kk = 0; kk < 4; ++kk) {
    const int pl = (4 * kk + q) * 128;
    bf8_t a[4], bb[2];
#pragma unroll
    for (int ma = 0; ma < 4; ++ma)
      a[ma] = *(const bf8_t*)(wo2 + (size_t)(16 * ma + li) * 128 + kk * 32 + q * 8);
#pragma unroll
    for (int nb = 0; nb < 2; ++nb)
      bb[nb] = *(const bf8_t*)&h1s[(pl + 32 * wv + 16 * nb + li) * 8];
#pragma unroll
    for (int ma = 0; ma < 4; ++ma)
#pragma unroll
      for (int nb = 0; nb < 2; ++nb)
        a2[ma][nb] = MFMA(a[ma], bb[nb], a2[ma][nb], 0, 0, 0);
  }
  // h2 -> h2s planar [c8chunk][s]; wave-private s rows (no barrier)
#pragma unroll
  for (int ma = 0; ma < 4; ++ma) {
    const int c80 = 16 * ma + 4 * q;
    f4_t bv = *(const f4_t*)(bo2 + c80);
#pragma unroll
    for (int nb = 0; nb < 2; ++nb) {
      const int sl = 32 * wv + 16 * nb + li;
      s4_t p;
#pragma unroll
      for (int r = 0; r < 4; ++r) p[r] = f2bf(fmaxf(a2[ma][nb][r] + bv[r], 0.0f));
      *(s4_t*)&h2s[((c80 >> 3) * 128 + sl) * 8 + (c80 & 7)] = p;
    }
  }
  // phase 3: occ = |Wo3 @ h2|  [o=64 x s=128], K=c8=64
  f4_t a3[4][2];
#pragma unroll
  for (int i = 0; i < 4; ++i) { a3[i][0] = fz; a3[i][1] = fz; }
#pragma unroll
  for (int kk = 0; kk < 2; ++kk) {
    const int pl = (4 * kk + q) * 128;
    bf8_t a[4], bb[2];
#pragma unroll
    for (int ma = 0; ma < 4; ++ma)
      a[ma] = *(const bf8_t*)(wo3 + (size_t)(16 * ma + li) * 64 + kk * 32 + q * 8);
#pragma unroll
    for (int nb = 0; nb < 2; ++nb)
      bb[nb] = *(const bf8_t*)&h2s[(pl + 32 * wv + 16 * nb + li) * 8];
#pragma unroll
    for (int ma = 0; ma < 4; ++ma)
#pragma unroll
      for (int nb = 0; nb < 2; ++nb)
        a3[ma][nb] = MFMA(a[ma], bb[nb], a3[ma][nb], 0, 0, 0);
  }
  // |.| -> occP planar tile [s8][o][s0]
  short* ot = occP + (size_t)(b * 128 + tile) * 8192;
#pragma unroll
  for (int ma = 0; ma < 4; ++ma)
#pragma unroll
    for (int nb = 0; nb < 2; ++nb) {
      const int o = 16 * ma + 4 * q;
      const int sl = 32 * wv + 16 * nb + li;
#pragma unroll
      for (int r = 0; r < 4; ++r)
        ot[(sl >> 3) * 512 + (o + r) * 8 + (sl & 7)] = f2bf(fabsf(a3[ma][nb][r]));
    }
  // sumocc[b][o] += sum_s |occ| (fp32)
#pragma unroll
  for (int ma = 0; ma < 4; ++ma)
#pragma unroll
    for (int r = 0; r < 4; ++r) {
      float v = fabsf(a3[ma][0][r]) + fabsf(a3[ma][1][r]);
#pragma unroll
      for (int m = 1; m < 16; m <<= 1) v += __shfl_xor(v, m, 64);
      if (li == 0) atomicAdd(&sumocc[b * 64 + 16 * ma + 4 * q + r], v);
    }
}

// ---------------- r1 GEMM + spatial contraction into M ----------------------
__global__ __launch_bounds__(256) void k_feat(
    const short* __restrict__ xTs, const short* __restrict__ w1s,
    const float* __restrict__ b1, const short* __restrict__ occP,
    float* __restrict__ M) {
  __shared__ short smem[32768];  // 64KB: buf0 | buf1
  short* const buf0 = smem;
  short* const buf1 = smem + 16384;
  short* const r1s = buf0;  // 32KB planar [schunk][j] after each K-loop
  const int sg = blockIdx.x, cb = blockIdx.y, b = blockIdx.z;
  const int t = threadIdx.x, lane = t & 63, wv = t >> 6;
  const int q = lane >> 4, li = lane & 15;
  const int mh = (wv & 1) * 64, nh = (wv >> 1) * 64;
  const short* w1b = w1s + (size_t)cb * 65536;  // [kc][k8][j][k0] for this jc
  const f4_t fz = {0.f, 0.f, 0.f, 0.f};

  float biasv[4];
#pragma unroll
  for (int nb = 0; nb < 4; ++nb) biasv[nb] = b1[cb * 128 + nh + 16 * nb + li];

  f4_t macc[4][2];
#pragma unroll
  for (int i = 0; i < 4; ++i) { macc[i][0] = fz; macc[i][1] = fz; }

  // prologue: tile0 chunk0 -> buf1
  {
    const short* xT0 = xTs + (size_t)(b * 128 + sg * 4) * 65536;
    stage16k(xT0, buf1, wv, lane);
    stage16k(w1b, buf1 + 8192, wv, lane);
  }

  for (int tt = 0; tt < 4; ++tt) {
    const int st = sg * 4 + tt;
    const short* xTb = xTs + (size_t)(b * 128 + st) * 65536;
    f4_t acc[4][4];
#pragma unroll
    for (int i = 0; i < 4; ++i)
#pragma unroll
      for (int j = 0; j < 4; ++j) acc[i][j] = fz;

    for (int i = 0; i < 8; ++i) {
      BAR_FENCE();  // A: prev chunk's (and prev contraction's) LDS reads done
      if (i < 7) {
        short* nb_ = (i & 1) ? buf1 : buf0;  // chunk i+1 -> buf[(i+2)&1]
        stage16k(xTb + (i + 1) * 8192, nb_, wv, lane);
        stage16k(w1b + (i + 1) * 8192, nb_ + 8192, wv, lane);
        WAIT_VM8();  // chunk-i landed; chunk-i+1 stays in flight
      } else {
        WAIT_VM0();
      }
      BAR_FENCE();  // B: all waves' chunk-i visible
      const short* xs = (i & 1) ? buf0 : buf1;
      const short* wsp = xs + 8192;
#pragma unroll
      for (int kk = 0; kk < 2; ++kk) {
        const int pl = (4 * kk + q) * 128;
        bf8_t a[4], bb[4];
#pragma unroll
        for (int ma = 0; ma < 4; ++ma)
          a[ma] = *(const bf8_t*)&xs[(pl + mh + 16 * ma + li) * 8];
#pragma unroll
        for (int nb = 0; nb < 4; ++nb)
          bb[nb] = *(const bf8_t*)&wsp[(pl + nh + 16 * nb + li) * 8];
#pragma unroll
        for (int ma = 0; ma < 4; ++ma)
#pragma unroll
          for (int nb = 0; nb < 4; ++nb)
            acc[ma][nb] = MFMA(a[ma], bb[nb], acc[ma][nb], 0, 0, 0);
      }
    }
    WAIT_LGKM0();
    BAR_FENCE();  // chunk7 (buf0) reads retired everywhere; buf0 reusable
    // r1 = relu(acc + b1) -> r1s planar [schunk][j] (buf0)
#pragma unroll
    for (int ma = 0; ma < 4; ++ma) {
      const int sl0 = mh + 16 * ma + 4 * q;  // 4 consecutive s
#pragma unroll
      for (int nb = 0; nb < 4; ++nb) {
        const int jl = nh + 16 * nb + li;
        s4_t p;
#pragma unroll
        for (int r = 0; r < 4; ++r)
          p[r] = f2bf(fmaxf(acc[ma][nb][r] + biasv[nb], 0.0f));
        *(s4_t*)&r1s[((sl0 >> 3) * 128 + jl) * 8 + (sl0 & 7)] = p;
      }
    }
    WAIT_LGKM0();
    BAR_FENCE();  // r1s visible to all waves
    // occ A-frags from global FIRST (older than prologue glds -> the
    // compiler's wait on them leaves the chunk0 prefetch in flight)
    const short* ot = occP + (size_t)(b * 128 + st) * 8192;
    bf8_t af[4][4];
#pragma unroll
    for (int kc = 0; kc < 4; ++kc)
#pragma unroll
      for (int ma = 0; ma < 4; ++ma)  // planar: 16 lanes read 256B contiguous
        af[ma][kc] = *(const bf8_t*)(ot + ((kc * 4 + q) * 64 + 16 * ma + li) * 8);
    // next tile's chunk0 prologue -> buf1 (chunk6 reads retired at i=7 A)
    if (tt < 3) {
      stage16k(xTb + 65536, buf1, wv, lane);
      stage16k(w1b, buf1 + 8192, wv, lane);
    }
    // M[o][j] += occ[o][s] * r1[j][s]  (K = s = 128)
#pragma unroll
    for (int kc = 0; kc < 4; ++kc) {
      const int pl = (4 * kc + q) * 128;
      bf8_t bb[2];
#pragma unroll
      for (int nb = 0; nb < 2; ++nb)
        bb[nb] = *(const bf8_t*)&r1s[(pl + 32 * wv + 16 * nb + li) * 8];
#pragma unroll
      for (int ma = 0; ma < 4; ++ma)
#pragma unroll
        for (int nb = 0; nb < 2; ++nb)
          macc[ma][nb] = MFMA(af[ma][kc], bb[nb], macc[ma][nb], 0, 0, 0);
    }
  }
  // flush partial M (64 x 128 per block) once
#pragma unroll
  for (int ma = 0; ma < 4; ++ma)
#pragma unroll
    for (int nb = 0; nb < 2; ++nb) {
      const int jg = cb * 128 + 32 * wv + 16 * nb + li;
#pragma unroll
      for (int r = 0; r < 4; ++r) {
        const int o = 16 * ma + 4 * q + r;
        atomicAdd(&M[((size_t)b * 64 + o) * 512 + jg], macc[ma][nb][r]);
      }
    }
}

// ---------------- epilogue: out = (M @ W2^T + sumocc * b2^T) / S ------------
// LDS-staged: block (cg,og,b) = 16o x 16c tile; stage M 16x512 + w2 16x512
// with coalesced f4 copies, compute from LDS (padded rows: no conflicts).
__global__ __launch_bounds__(256) void k_out(
    const float* __restrict__ M, const float* __restrict__ sumocc,
    const float* __restrict__ w2, const float* __restrict__ b2,
    float* __restrict__ out) {
  __shared__ float Mlds[16][516];
  __shared__ float Wlds[16][516];
  const int cg = blockIdx.x, og = blockIdx.y, b = blockIdx.z;
  const int t = threadIdx.x;
  const float* Msrc = M + ((size_t)b * 64 + og * 16) * 512;
  const float* Wsrc = w2 + (size_t)cg * 16 * 512;
#pragma unroll
  for (int k = 0; k < 8; ++k) {
    const int fi = k * 256 + t;              // f4 index 0..2047
    const int row = fi >> 7, col = (fi & 127) * 4;
    *(f4_t*)&Mlds[row][col] = *(const f4_t*)(Msrc + row * 512 + col);
    *(f4_t*)&Wlds[row][col] = *(const f4_t*)(Wsrc + row * 512 + col);
  }
  __syncthreads();
  const int o = t >> 4, c = t & 15;
  float s0 = 0.f, s1 = 0.f;
#pragma unroll 8
  for (int j = 0; j < 512; j += 8) {
    f4_t m0 = *(const f4_t*)&Mlds[o][j];
    f4_t w0 = *(const f4_t*)&Wlds[c][j];
    f4_t m1 = *(const f4_t*)&Mlds[o][j + 4];
    f4_t w1 = *(const f4_t*)&Wlds[c][j + 4];
    s0 += m0[0] * w0[0] + m0[1] * w0[1] + m0[2] * w0[2] + m0[3] * w0[3];
    s1 += m1[0] * w1[0] + m1[1] * w1[1] + m1[2] * w1[2] + m1[3] * w1[3];
  }
  const int og_ = og * 16 + o, cg_ = cg * 16 + c;
  out[((size_t)b * 64 + og_) * 512 + cg_] =
      ((s0 + s1) + sumocc[b * 64 + og_] * b2[cg_]) * (1.0f / 16384.0f);
}

// ---------------- launch ----------------------------------------------------
// ws layout (bytes):
//   0         xTs     4*16384*512 bf16 = 67108864   (swizzled tiles)
//   67108864  wb      339968 bf16 (w1s | wo1s | wo2 | wo3) = 679936
//   67788800  occP    4*64*16384 bf16  = 8388608    (planar tiles)
//   76177408  M       4*64*512 fp32    = 524288
//   76701696  sumocc  256 fp32         = 1024
extern "C" void kernel_launch(void* const* d_in, const int* in_sizes, int n_in,
                              void* d_out, int out_size, void* d_ws, size_t ws_size,
                              hipStream_t stream) {
  (void)in_sizes; (void)n_in; (void)out_size; (void)ws_size;
  const float* x      = (const float*)d_in[0];
  const float* w_add1 = (const float*)d_in[1];
  const float* b_add1 = (const float*)d_in[2];
  const float* w_add2 = (const float*)d_in[3];
  const float* b_add2 = (const float*)d_in[4];
  const float* w_occ1 = (const float*)d_in[5];
  const float* b_occ1 = (const float*)d_in[6];
  const float* w_occ2 = (const float*)d_in[7];
  const float* b_occ2 = (const float*)d_in[8];
  const float* w_occ3 = (const float*)d_in[9];

  char* ws = (char*)d_ws;
  short* xTs     = (short*)(ws);
  short* wb      = (short*)(ws + 67108864);
  short* occP    = (short*)(ws + 67788800);
  float* M       = (float*)(ws + 76177408);
  float* sumocc  = (float*)(ws + 76701696);

  hipMemsetAsync(M, 0, 524288 + 1024, stream);  // M + sumocc
  k_transpose<<<dim3(128, 8, 4), dim3(256), 0, stream>>>(
      x, xTs, w_add1, w_occ1, w_occ2, w_occ3, wb);

  const short* w1sp = wb;
  const short* wbo1 = wb + 262144;
  const short* wbo2 = wb + 327680;
  const short* wbo3 = wb + 335872;
  k_occ<<<dim3(128, 4), dim3(256), 0, stream>>>(xTs, wbo1, wbo2, wbo3,
                                                b_occ1, b_occ2, occP, sumocc);
  k_feat<<<dim3(32, 4, 4), dim3(256), 0, stream>>>(xTs, w1sp, b_add1, occP, M);
  k_out<<<dim3(32, 4, 4), dim3(256), 0, stream>>>(M, sumocc, w_add2, b_add2,
                                                  (float*)d_out);
}